// Round 4
// baseline (718.858 us; speedup 1.0000x reference)
//
#include <hip/hip_runtime.h>

typedef _Float16 f16x8 __attribute__((ext_vector_type(8)));
typedef _Float16 f16x4 __attribute__((ext_vector_type(4)));
typedef float f32x4 __attribute__((ext_vector_type(4)));

#define NA 512
#define NB 512
#define NV 32
#define ND 512
#define NBV (NB * NV)  // 16384

// ---- K0: prep. Flat f16 converts for the scores GEMM inputs. ----
__global__ __launch_bounds__(256) void k_prep(const float* __restrict__ text,
                                              const float* __restrict__ video,
                                              _Float16* __restrict__ Tf,
                                              _Float16* __restrict__ Vf) {
  int b = blockIdx.x, t = threadIdx.x;
  const float* vb = video + (size_t)b * NV * ND;
  _Float16* ob = Vf + (size_t)b * NV * ND;
  for (int i = 0; i < 16; ++i) {
    int off = i * 1024 + t * 4;
    f32x4 x = *(const f32x4*)(vb + off);
    f16x4 h;
    h[0] = (_Float16)x[0]; h[1] = (_Float16)x[1];
    h[2] = (_Float16)x[2]; h[3] = (_Float16)x[3];
    *(f16x4*)(ob + off) = h;
  }
  if (b < 256) {
    int idx = (b * 256 + t) * 4;
    f32x4 x = *(const f32x4*)(text + idx);
    f16x4 h;
    h[0] = (_Float16)x[0]; h[1] = (_Float16)x[1];
    h[2] = (_Float16)x[2]; h[3] = (_Float16)x[3];
    *(f16x4*)(Tf + idx) = h;
  }
}

// XOR-swizzled LDS offset: row-major [row][32 f16], chunk = 8 f16.
__device__ inline int swz(int row, int ch) {
  return row * 32 + ((ch ^ ((row >> 1) & 3)) * 8);
}

// ---- K1: scores GEMM (f16 MFMA) + fused softmax over v -> Wf[a][b*32+v] f32
// VERBATIM round-1 structure (harness-verified); only the epilogue store
// type changed f16 -> f32 (pool consumes float weights, zero converts).
__global__ __launch_bounds__(256) void k_scores(const _Float16* __restrict__ Tf,
                                                const _Float16* __restrict__ Vf,
                                                float* __restrict__ Wf) {
  __shared__ _Float16 As[64 * 32];   // 4 KB
  __shared__ _Float16 Bs[128 * 32];  // 8 KB
  int t = threadIdx.x;
  int m0 = blockIdx.y * 64, n0 = blockIdx.x * 128;
  int w = t >> 6, lane = t & 63, ln = lane & 15, q = lane >> 4;
  int wm = (w >> 1) * 32, wn = (w & 1) * 64;
  int ra = t >> 2, ca = t & 3;        // As staging: row 0..63, chunk 0..3
  int rb = t >> 1, cb = (t & 1) * 2;  // Bs staging: row 0..127, chunks cb,cb+1
  const _Float16* tA = Tf + (size_t)(m0 + ra) * ND + ca * 8;
  const _Float16* tB = Vf + (size_t)(n0 + rb) * ND + cb * 8;
  f32x4 acc[2][4];
  for (int i = 0; i < 2; ++i)
    for (int j = 0; j < 4; ++j) acc[i][j] = (f32x4){0.f, 0.f, 0.f, 0.f};

  for (int kk = 0; kk < 16; ++kk) {
    int k0 = kk * 32;
    __syncthreads();
    *(f16x8*)(As + swz(ra, ca)) = *(const f16x8*)(tA + k0);
    *(f16x8*)(Bs + swz(rb, cb)) = *(const f16x8*)(tB + k0);
    *(f16x8*)(Bs + swz(rb, cb + 1)) = *(const f16x8*)(tB + k0 + 8);
    __syncthreads();
    f16x8 af[2], bf[4];
    for (int mt = 0; mt < 2; ++mt)
      af[mt] = *(const f16x8*)(As + swz(wm + mt * 16 + ln, q));
    for (int nt = 0; nt < 4; ++nt)
      bf[nt] = *(const f16x8*)(Bs + swz(wn + nt * 16 + ln, q));
    for (int mt = 0; mt < 2; ++mt)
      for (int nt = 0; nt < 4; ++nt)
        acc[mt][nt] = __builtin_amdgcn_mfma_f32_16x16x32_f16(af[mt], bf[nt],
                                                             acc[mt][nt], 0, 0, 0);
  }

  // Softmax over each 32-col group (one b): cols g*32.. = n-tiles {2g, 2g+1}.
  // C/D layout: row(m) = q*4+r, col(n) = ln. Row-reduce across 16 lanes (same q).
  const float invT = 0.2f;  // 1/TEMP
  for (int mt = 0; mt < 2; ++mt) {
    for (int g = 0; g < 2; ++g) {
      for (int r = 0; r < 4; ++r) {
        float v0 = acc[mt][2 * g][r] * invT;
        float v1 = acc[mt][2 * g + 1][r] * invT;
        float mx = fmaxf(v0, v1);
        for (int msk = 1; msk < 16; msk <<= 1)
          mx = fmaxf(mx, __shfl_xor(mx, msk, 16));
        float p0 = __expf(v0 - mx), p1 = __expf(v1 - mx);
        float s = p0 + p1;
        for (int msk = 1; msk < 16; msk <<= 1)
          s += __shfl_xor(s, msk, 16);
        float inv = 1.0f / s;
        int a = m0 + wm + mt * 16 + q * 4 + r;
        int col = n0 + wn + g * 32 + ln;
        Wf[(size_t)a * NBV + col] = p0 * inv;
        Wf[(size_t)a * NBV + col + 16] = p1 * inv;
      }
    }
  }
}

// ---- K2: out[a][b][d] = sum_v Wf[a][b*32+v] * video[b][v][d]
// Pure fp32 fmaf (no MFMA, no dot builtins, no LDS, no barriers).
// Lanes along d -> every store is a contiguous 1 KB wave-store.
// Block: one b, 64 a (wave w owns a0+w*16 .. +15), d in two 256-wide halves.
// video[b] half held in registers (32 x f32x4), reused across 16 a-rows.
__global__ __launch_bounds__(256) void k_pool(const float* __restrict__ Wf,
                                              const float* __restrict__ video,
                                              float* __restrict__ out) {
  int b = blockIdx.x, t = threadIdx.x;
  int w = t >> 6, lane = t & 63;
  int a0 = blockIdx.y * 64 + w * 16;
  const float* vb = video + (size_t)b * NV * ND;
  for (int c = 0; c < 2; ++c) {
    f32x4 vr[32];
#pragma unroll
    for (int v = 0; v < 32; ++v)
      vr[v] = *(const f32x4*)(vb + (size_t)v * ND + c * 256 + lane * 4);
    for (int i = 0; i < 16; ++i) {
      int a = a0 + i;
      const f32x4* wrow = (const f32x4*)(Wf + (size_t)a * NBV + b * NV);
      f32x4 s = (f32x4){0.f, 0.f, 0.f, 0.f};
#pragma unroll
      for (int k = 0; k < 8; ++k) {
        f32x4 wv = wrow[k];
#pragma unroll
        for (int e = 0; e < 4; ++e) {
          float wgt = wv[e];
          int v = k * 4 + e;
          s[0] = fmaf(wgt, vr[v][0], s[0]);
          s[1] = fmaf(wgt, vr[v][1], s[1]);
          s[2] = fmaf(wgt, vr[v][2], s[2]);
          s[3] = fmaf(wgt, vr[v][3], s[3]);
        }
      }
      *(f32x4*)(out + ((size_t)a * NB + b) * ND + c * 256 + lane * 4) = s;
    }
  }
}

extern "C" void kernel_launch(void* const* d_in, const int* in_sizes, int n_in,
                              void* d_out, int out_size, void* d_ws, size_t ws_size,
                              hipStream_t stream) {
  const float* text = (const float*)d_in[0];
  const float* video = (const float*)d_in[1];
  float* out = (float*)d_out;
  // workspace: Wf f32 32MB | Vf f16 16MB | Tf f16 0.5MB  = 48.5 MB
  float* Wf = (float*)d_ws;
  _Float16* Vf = (_Float16*)((char*)d_ws + (size_t)32 * 1024 * 1024);
  _Float16* Tf = (_Float16*)((char*)d_ws + (size_t)48 * 1024 * 1024);
  k_prep<<<dim3(NB), 256, 0, stream>>>(text, video, Tf, Vf);
  k_scores<<<dim3(NBV / 128, NA / 64), 256, 0, stream>>>(Tf, Vf, Wf);
  k_pool<<<dim3(NB, NA / 64), 256, 0, stream>>>(Wf, video, out);
}